// Round 1
// baseline (592.843 us; speedup 1.0000x reference)
//
#include <hip/hip_runtime.h>

typedef unsigned short u16;
typedef __attribute__((ext_vector_type(4))) float f32x4;
typedef __attribute__((ext_vector_type(8))) short bf16x8;

#define AS1 __attribute__((address_space(1)))
#define AS3 __attribute__((address_space(3)))

__device__ __forceinline__ float bf2f(u16 u) {
  union { unsigned int i; float f; } v; v.i = ((unsigned int)u) << 16; return v.f;
}
__device__ __forceinline__ u16 f2bf(float f) {
  union { float f; unsigned int i; } v; v.f = f;
  unsigned int r = v.i + 0x7fffu + ((v.i >> 16) & 1u);  // RNE
  return (u16)(r >> 16);
}
__device__ __forceinline__ void gload16(const void* g, void* l) {
  // async global->LDS, 16B/lane; LDS dest = wave-uniform base + lane*16
  __builtin_amdgcn_global_load_lds((const AS1 unsigned int*)g, (AS3 unsigned int*)l, 16, 0, 0);
}

struct GemmDesc {
  const u16* A;     // [M][K] bf16 row-major
  const u16* Bt;    // [N][K] bf16 row-major (B transposed)
  const u16* Cadd;  // optional bf16 [M][N] addend
  const float* Fadd;// optional f32  [M][N] addend
  u16* D;           // optional bf16 [M][N] out
  u16* Dt;          // optional bf16 [N][M] out (transposed)
  float* Df;        // optional f32  [M][N] out
  int M, N, K, tn, tiles;
  float scale;      // out = scale*(acc + adds)
};
struct GemmBatch { GemmDesc d[3]; int nd; };

// D = A @ Bt^T (+adds), bf16 in, f32 acc. BMxBN tile, BK=64, 4 waves (2x2),
// each wave (BM/2)x(BN/2) via 16x16x32 bf16 MFMA.
template<int BM, int BN>
__global__ __launch_bounds__(256) void gemm_bt(GemmBatch b) {
  // XCD-aware swizzle (all grids are multiples of 8)
  const int nwg = gridDim.x;
  int t = ((blockIdx.x & 7) * (nwg >> 3)) + (blockIdx.x >> 3);
  int di = 0;
  while (di + 1 < b.nd && t >= b.d[di].tiles) { t -= b.d[di].tiles; ++di; }
  const GemmDesc d = b.d[di];
  const int tm = t / d.tn, tnn = t - tm * d.tn;
  const int m0 = tm * BM, n0 = tnn * BN;
  const int lane = threadIdx.x & 63;
  const int w = threadIdx.x >> 6;
  const int wm = w >> 1, wn = w & 1;
  constexpr int FM = BM / 32, FN = BN / 32;
  __shared__ __align__(16) u16 Asm[BM * 64];
  __shared__ __align__(16) u16 Bsm[BN * 64];
  f32x4 acc[FM][FN];
  #pragma unroll
  for (int i = 0; i < FM; ++i)
    #pragma unroll
    for (int j = 0; j < FN; ++j)
      acc[i][j] = (f32x4){0.f, 0.f, 0.f, 0.f};
  const int srow = lane >> 3, scol = (lane & 7) << 3;
  const int K = d.K;
  for (int k0 = 0; k0 < K; k0 += 64) {
    __syncthreads();
    #pragma unroll
    for (int c = w; c < BM / 8; c += 4)
      gload16(d.A + (size_t)(m0 + c * 8 + srow) * K + k0 + scol, &Asm[c * 512]);
    #pragma unroll
    for (int c = w; c < BN / 8; c += 4)
      gload16(d.Bt + (size_t)(n0 + c * 8 + srow) * K + k0 + scol, &Bsm[c * 512]);
    __syncthreads();
    #pragma unroll
    for (int kk = 0; kk < 64; kk += 32) {
      bf16x8 af[FM], bfr[FN];
      #pragma unroll
      for (int i = 0; i < FM; ++i)
        af[i] = *(const bf16x8*)&Asm[(wm * (BM / 2) + i * 16 + (lane & 15)) * 64 + kk + ((lane >> 4) << 3)];
      #pragma unroll
      for (int j = 0; j < FN; ++j)
        bfr[j] = *(const bf16x8*)&Bsm[(wn * (BN / 2) + j * 16 + (lane & 15)) * 64 + kk + ((lane >> 4) << 3)];
      #pragma unroll
      for (int i = 0; i < FM; ++i)
        #pragma unroll
        for (int j = 0; j < FN; ++j)
          acc[i][j] = __builtin_amdgcn_mfma_f32_16x16x32_bf16(af[i], bfr[j], acc[i][j], 0, 0, 0);
    }
  }
  const int r4 = (lane >> 4) << 2;
  const int cc = lane & 15;
  #pragma unroll
  for (int i = 0; i < FM; ++i) {
    #pragma unroll
    for (int j = 0; j < FN; ++j) {
      const int row0 = m0 + wm * (BM / 2) + i * 16 + r4;
      const int col = n0 + wn * (BN / 2) + j * 16 + cc;
      float v[4];
      #pragma unroll
      for (int q = 0; q < 4; ++q) v[q] = acc[i][j][q];
      if (d.Cadd) {
        #pragma unroll
        for (int q = 0; q < 4; ++q) v[q] += bf2f(d.Cadd[(size_t)(row0 + q) * d.N + col]);
      }
      if (d.Fadd) {
        #pragma unroll
        for (int q = 0; q < 4; ++q) v[q] += d.Fadd[(size_t)(row0 + q) * d.N + col];
      }
      if (d.scale != 1.0f) {
        #pragma unroll
        for (int q = 0; q < 4; ++q) v[q] *= d.scale;
      }
      if (d.D) {
        #pragma unroll
        for (int q = 0; q < 4; ++q) d.D[(size_t)(row0 + q) * d.N + col] = f2bf(v[q]);
      }
      if (d.Df) {
        #pragma unroll
        for (int q = 0; q < 4; ++q) d.Df[(size_t)(row0 + q) * d.N + col] = v[q];
      }
      if (d.Dt) {
        ushort4 pk = make_ushort4(f2bf(v[0]), f2bf(v[1]), f2bf(v[2]), f2bf(v[3]));
        *(ushort4*)&d.Dt[(size_t)col * d.M + row0] = pk;
      }
    }
  }
}

// f32 -> bf16 straight convert (n4 = n/4)
__global__ __launch_bounds__(256) void conv_s(const float* in, u16* out, int n4) {
  int idx = blockIdx.x * 256 + threadIdx.x;
  int stride = gridDim.x * 256;
  for (int i = idx; i < n4; i += stride) {
    float4 f = ((const float4*)in)[i];
    ushort4 o = make_ushort4(f2bf(f.x), f2bf(f.y), f2bf(f.z), f2bf(f.w));
    ((ushort4*)out)[i] = o;
  }
}

// out[C][R] = bf16(in[r][c]) ; R,C multiples of 64
__global__ __launch_bounds__(256) void conv_t(const float* in, u16* out, int R, int C) {
  __shared__ float tile[64][65];
  int tiles_c = C >> 6;
  int tr = blockIdx.x / tiles_c;
  int tc = blockIdx.x - tr * tiles_c;
  int r0 = tr << 6, c0 = tc << 6;
  int lr = threadIdx.x >> 6;
  int lc = threadIdx.x & 63;
  #pragma unroll
  for (int p = 0; p < 16; ++p) {
    int r = p * 4 + lr;
    tile[r][lc] = in[(size_t)(r0 + r) * C + c0 + lc];
  }
  __syncthreads();
  #pragma unroll
  for (int p = 0; p < 16; ++p) {
    int r = p * 4 + lr;  // row in output tile == input column c0+r
    out[(size_t)(c0 + r) * R + r0 + lc] = f2bf(tile[lc][r]);
  }
}

// v[j] = sum_i C[i][j], C: [rows][cols] f32
__global__ __launch_bounds__(256) void colsum(const float* Cm, float* v, int rows, int cols) {
  int j = blockIdx.x * 256 + threadIdx.x;
  if (j >= cols) return;
  float s = 0.f;
  for (int i = 0; i < rows; ++i) s += Cm[(size_t)i * cols + j];
  v[j] = s;
}

// tout = tin + M @ tin ; M bf16 [n][n], n=2048. 4 rows/block (1/wave).
__global__ __launch_bounds__(256) void matvec_add(const u16* Mtx, const float* tin, float* tout, int n) {
  __shared__ float ts[2048];
  for (int i = threadIdx.x; i < n; i += 256) ts[i] = tin[i];
  __syncthreads();
  int w = threadIdx.x >> 6, lane = threadIdx.x & 63;
  int row = blockIdx.x * 4 + w;
  float s = 0.f;
  for (int k0 = lane * 8; k0 < n; k0 += 512) {
    bf16x8 mv = *(const bf16x8*)&Mtx[(size_t)row * n + k0];
    #pragma unroll
    for (int e = 0; e < 8; ++e) s += bf2f((u16)mv[e]) * ts[k0 + e];
  }
  #pragma unroll
  for (int off = 32; off > 0; off >>= 1) s += __shfl_down(s, off);
  if (lane == 0) tout[row] = ts[row] + s;
}

// u[row] = dot(Cm[row], t) ; Cm f32 [rows][n]
__global__ __launch_bounds__(256) void matvec_f32(const float* Cm, const float* t, float* u, int rows, int n) {
  __shared__ float ts[2048];
  for (int i = threadIdx.x; i < n; i += 256) ts[i] = t[i];
  __syncthreads();
  int w = threadIdx.x >> 6, lane = threadIdx.x & 63;
  int row = blockIdx.x * 4 + w;
  if (row >= rows) return;
  float s = 0.f;
  for (int k0 = lane * 4; k0 < n; k0 += 256) {
    float4 c4 = *(const float4*)&Cm[(size_t)row * n + k0];
    s += c4.x * ts[k0] + c4.y * ts[k0 + 1] + c4.z * ts[k0 + 2] + c4.w * ts[k0 + 3];
  }
  #pragma unroll
  for (int off = 32; off > 0; off >>= 1) s += __shfl_down(s, off);
  if (lane == 0) u[row] = s;
}

// D_hat[i][j] = 0.5*(1-u[i])/512 + 0.5*DF[i][j], 512x512
__global__ __launch_bounds__(256) void dhat_k(const float* DF, const float* u, float* out) {
  int idx = blockIdx.x * 256 + threadIdx.x;
  int i = idx >> 9;
  out[idx] = 0.5f * (1.0f - u[i]) * (1.0f / 512.0f) + 0.5f * DF[idx];
}

extern "C" void kernel_launch(void* const* d_in, const int* in_sizes, int n_in,
                              void* d_out, int out_size, void* d_ws, size_t ws_size,
                              hipStream_t stream) {
  (void)in_sizes; (void)n_in; (void)out_size; (void)ws_size;
  const float* Cf  = (const float*)d_in[0];  // [512][2048]
  const float* Af  = (const float*)d_in[1];  // [2048][2048]
  const float* AFf = (const float*)d_in[2];  // [2048][2048]
  const float* BFf = (const float*)d_in[3];  // [2048][512]
  const float* CFf = (const float*)d_in[4];  // [512][2048]
  const float* DFf = (const float*)d_in[5];  // [512][512]
  float* out = (float*)d_out;                // B_hat [2048][512] ++ D_hat [512][512]

  const size_t SLOT = 2048ull * 2048ull * 2ull;  // 8 MiB
  char* ws = (char*)d_ws;
  auto slot = [&](int i) { return (u16*)(ws + (size_t)i * SLOT); };
  // M = A^T, N = A_F ; *_T buffers hold the transposed (Bt-form) copies
  u16* Mb  = slot(0);  // M0 = A^T
  u16* MbT = slot(1);  // M0^T = A
  u16* MA  = slot(2);  // M1, later M3 (= M^8)
  u16* MB_ = slot(3);  // M2
  u16* MTA = slot(4);  // M1^T
  u16* MTB = slot(5);  // M2^T
  u16* Nb  = slot(6);  // N0 = A_F
  u16* NbT = slot(7);  // N0^T
  u16* NA  = slot(8);  // N1, later N3 (= N^8)
  u16* NB_ = slot(9);  // N2
  u16* NTA = slot(10); // N1^T
  u16* NTB = slot(11); // N2^T
  u16* SA  = slot(12); // X(=S0), later S2
  u16* SB  = slot(13); // S1, later S3
  u16* STx = slot(14); // X^T / S1^T / S2^T (rotating)
  u16* Tb  = slot(15); // T0/T1/T2
  char* sk = ws + 16 * SLOT;
  u16* CtB = (u16*)(sk + (0ull << 20));   // C^T   [2048][512]
  u16* CFT = (u16*)(sk + (2ull << 20));   // C_F^T [2048][512]
  u16* BFT = (u16*)(sk + (4ull << 20));   // B_F^T [512][2048]
  u16* YT  = (u16*)(sk + (6ull << 20));   // (N^8 B_F)^T [512][2048]
  u16* Z1T = (u16*)(sk + (8ull << 20));   // (S8 Y)^T    [512][2048]
  float* Z0 = (float*)(sk + (10ull << 20)); // S8 B_F f32 [2048][512]
  float* vv = (float*)(sk + (14ull << 20));
  float* ta = vv + 4096;
  float* tb = ta + 4096;
  float* uu = tb + 4096;

  auto mk = [](const u16* A, const u16* Bt, const u16* Cadd, const float* Fadd,
               u16* D, u16* Dt, float* Df, int M, int N, int K, float scale, int tile) {
    GemmDesc g; g.A = A; g.Bt = Bt; g.Cadd = Cadd; g.Fadd = Fadd;
    g.D = D; g.Dt = Dt; g.Df = Df; g.M = M; g.N = N; g.K = K;
    g.tn = N / tile; g.tiles = (M / tile) * (N / tile); g.scale = scale; return g;
  };

  // ---- input conversion ----
  conv_s<<<2048, 256, 0, stream>>>(Af, MbT, 4194304 / 4);
  conv_s<<<2048, 256, 0, stream>>>(AFf, Nb, 4194304 / 4);
  conv_t<<<1024, 256, 0, stream>>>(Af, Mb, 2048, 2048);
  conv_t<<<1024, 256, 0, stream>>>(AFf, NbT, 2048, 2048);
  conv_t<<<256, 256, 0, stream>>>(Cf, CtB, 512, 2048);
  conv_t<<<256, 256, 0, stream>>>(CFf, CFT, 512, 2048);
  conv_t<<<256, 256, 0, stream>>>(BFf, BFT, 2048, 512);
  colsum<<<8, 256, 0, stream>>>(Cf, vv, 512, 2048);

  // ---- P0: X = C^T @ C_F (dual-write X, X^T) ----
  { GemmBatch gb{}; gb.nd = 1;
    gb.d[0] = mk(CtB, CFT, nullptr, nullptr, SA, STx, nullptr, 2048, 2048, 512, 1.f, 128);
    gemm_bt<128, 128><<<256, 256, 0, stream>>>(gb); }
  // t1 = v + M v
  matvec_add<<<512, 256, 0, stream>>>(Mb, vv, ta, 2048);
  // ---- P1: T0 = M@X | M1 = M@M | N1 = N@N ----
  { GemmBatch gb{}; gb.nd = 3;
    gb.d[0] = mk(Mb, STx, nullptr, nullptr, Tb, nullptr, nullptr, 2048, 2048, 2048, 1.f, 128);
    gb.d[1] = mk(Mb, MbT, nullptr, nullptr, MA, MTA, nullptr, 2048, 2048, 2048, 1.f, 128);
    gb.d[2] = mk(Nb, NbT, nullptr, nullptr, NA, NTA, nullptr, 2048, 2048, 2048, 1.f, 128);
    gemm_bt<128, 128><<<768, 256, 0, stream>>>(gb); }
  // t2 = t1 + M1 t1
  matvec_add<<<512, 256, 0, stream>>>(MA, ta, tb, 2048);
  // ---- P2: S1 = X + T0@N (Bt=N^T) | M2 = M1@M1 ----
  { GemmBatch gb{}; gb.nd = 2;
    gb.d[0] = mk(Tb, NbT, SA, nullptr, SB, STx, nullptr, 2048, 2048, 2048, 1.f, 128);
    gb.d[1] = mk(MA, MTA, nullptr, nullptr, MB_, MTB, nullptr, 2048, 2048, 2048, 1.f, 128);
    gemm_bt<128, 128><<<512, 256, 0, stream>>>(gb); }
  // t3 = t2 + M2 t2
  matvec_add<<<512, 256, 0, stream>>>(MB_, tb, ta, 2048);
  // ---- P3: T1 = M1@S1 (Bt=S1^T) | N2 = N1@N1 ----
  { GemmBatch gb{}; gb.nd = 2;
    gb.d[0] = mk(MA, STx, nullptr, nullptr, Tb, nullptr, nullptr, 2048, 2048, 2048, 1.f, 128);
    gb.d[1] = mk(NA, NTA, nullptr, nullptr, NB_, NTB, nullptr, 2048, 2048, 2048, 1.f, 128);
    gemm_bt<128, 128><<<512, 256, 0, stream>>>(gb); }
  // ---- P4: S2 = S1 + T1@N1 (Bt=N1^T) | M3 = M2@M2 (no T-out) ----
  { GemmBatch gb{}; gb.nd = 2;
    gb.d[0] = mk(Tb, NTA, SB, nullptr, SA, STx, nullptr, 2048, 2048, 2048, 1.f, 128);
    gb.d[1] = mk(MB_, MTB, nullptr, nullptr, MA, nullptr, nullptr, 2048, 2048, 2048, 1.f, 128);
    gemm_bt<128, 128><<<512, 256, 0, stream>>>(gb); }
  // t4 = t3 + M3 t3  (t4 = sum_{k<16} M^k v)
  matvec_add<<<512, 256, 0, stream>>>(MA, ta, tb, 2048);
  // ---- P5: T2 = M2@S2 (Bt=S2^T) | N3 = N2@N2 (no T-out) ----
  { GemmBatch gb{}; gb.nd = 2;
    gb.d[0] = mk(MB_, STx, nullptr, nullptr, Tb, nullptr, nullptr, 2048, 2048, 2048, 1.f, 128);
    gb.d[1] = mk(NB_, NTB, nullptr, nullptr, NA, nullptr, nullptr, 2048, 2048, 2048, 1.f, 128);
    gemm_bt<128, 128><<<512, 256, 0, stream>>>(gb); }
  // ---- P6: S3 = S2 + T2@N2 (Bt=N2^T) | Y^T: Y = N3@B_F (write Dt only) ----
  { GemmBatch gb{}; gb.nd = 2;
    gb.d[0] = mk(Tb, NTB, SA, nullptr, SB, nullptr, nullptr, 2048, 2048, 2048, 1.f, 128);
    gb.d[1] = mk(NA, BFT, nullptr, nullptr, nullptr, YT, nullptr, 2048, 512, 2048, 1.f, 128);
    gemm_bt<128, 128><<<320, 256, 0, stream>>>(gb); }
  // ---- P7 (64x64): Z0 = S3@B_F (f32) | Z1 = S3@Y (write Z1^T) ----
  { GemmBatch gb{}; gb.nd = 2;
    gb.d[0] = mk(SB, BFT, nullptr, nullptr, nullptr, nullptr, Z0, 2048, 512, 2048, 1.f, 64);
    gb.d[1] = mk(SB, YT, nullptr, nullptr, nullptr, Z1T, nullptr, 2048, 512, 2048, 1.f, 64);
    gemm_bt<64, 64><<<512, 256, 0, stream>>>(gb); }
  // ---- P8 (64x64): B_hat = -(M3@Z1 + Z0) -> d_out (f32) ----
  { GemmBatch gb{}; gb.nd = 1;
    gb.d[0] = mk(MA, Z1T, nullptr, Z0, nullptr, nullptr, out, 2048, 512, 2048, -1.f, 64);
    gemm_bt<64, 64><<<256, 256, 0, stream>>>(gb); }
  // ---- D_hat ----
  matvec_f32<<<128, 256, 0, stream>>>(Cf, tb, uu, 512, 2048);
  dhat_k<<<1024, 256, 0, stream>>>(DFf, uu, out + 2048 * 512);
}

// Round 2
// 358.106 us; speedup vs baseline: 1.6555x; 1.6555x over previous
//
#include <hip/hip_runtime.h>

typedef unsigned short u16;
typedef __attribute__((ext_vector_type(4))) float f32x4;
typedef __attribute__((ext_vector_type(8))) short bf16x8;

#define AS1 __attribute__((address_space(1)))
#define AS3 __attribute__((address_space(3)))

__device__ __forceinline__ float bf2f(u16 u) {
  union { unsigned int i; float f; } v; v.i = ((unsigned int)u) << 16; return v.f;
}
__device__ __forceinline__ u16 f2bf(float f) {
  union { float f; unsigned int i; } v; v.f = f;
  unsigned int r = v.i + 0x7fffu + ((v.i >> 16) & 1u);  // RNE
  return (u16)(r >> 16);
}
__device__ __forceinline__ void gload16(const void* g, void* l) {
  __builtin_amdgcn_global_load_lds((const AS1 unsigned int*)g, (AS3 unsigned int*)l, 16, 0, 0);
}

struct GemmDesc {
  const u16* A;     // [M][K] bf16 row-major
  const u16* Bt;    // [N][K] bf16 row-major (B transposed)
  const u16* Cadd;  // optional bf16 [M][N] addend
  const float* Fadd;// optional f32  [M][N] addend
  u16* D;           // optional bf16 [M][N] out
  u16* Dt;          // optional bf16 [N][M] out (transposed)
  float* Df;        // optional f32  [M][N] out
  int M, N, K, tn, tiles;
  float scale;
};
struct GemmBatch { GemmDesc d[3]; int nd; };

// D = A @ Bt^T (+adds), bf16 in, f32 acc. BMxBN tile, BK=64, 4 waves (2x2).
template<int BM, int BN>
__global__ __launch_bounds__(256) void gemm_bt(GemmBatch b) {
  const int nwg = gridDim.x;  // multiple of 8
  int t = ((blockIdx.x & 7) * (nwg >> 3)) + (blockIdx.x >> 3);
  int di = 0;
  while (di + 1 < b.nd && t >= b.d[di].tiles) { t -= b.d[di].tiles; ++di; }
  const GemmDesc d = b.d[di];
  const int tm = t / d.tn, tnn = t - tm * d.tn;
  const int m0 = tm * BM, n0 = tnn * BN;
  const int lane = threadIdx.x & 63;
  const int w = threadIdx.x >> 6;
  const int wm = w >> 1, wn = w & 1;
  constexpr int FM = BM / 32, FN = BN / 32;
  __shared__ __align__(16) u16 Asm[BM * 64];
  __shared__ __align__(16) u16 Bsm[BN * 64];
  f32x4 acc[FM][FN];
  #pragma unroll
  for (int i = 0; i < FM; ++i)
    #pragma unroll
    for (int j = 0; j < FN; ++j)
      acc[i][j] = (f32x4){0.f, 0.f, 0.f, 0.f};
  const int srow = lane >> 3, scol = (lane & 7) << 3;
  const int K = d.K;
  for (int k0 = 0; k0 < K; k0 += 64) {
    __syncthreads();
    #pragma unroll
    for (int c = w; c < BM / 8; c += 4)
      gload16(d.A + (size_t)(m0 + c * 8 + srow) * K + k0 + scol, &Asm[c * 512]);
    #pragma unroll
    for (int c = w; c < BN / 8; c += 4)
      gload16(d.Bt + (size_t)(n0 + c * 8 + srow) * K + k0 + scol, &Bsm[c * 512]);
    __syncthreads();
    #pragma unroll
    for (int kk = 0; kk < 64; kk += 32) {
      bf16x8 af[FM], bfr[FN];
      #pragma unroll
      for (int i = 0; i < FM; ++i)
        af[i] = *(const bf16x8*)&Asm[(wm * (BM / 2) + i * 16 + (lane & 15)) * 64 + kk + ((lane >> 4) << 3)];
      #pragma unroll
      for (int j = 0; j < FN; ++j)
        bfr[j] = *(const bf16x8*)&Bsm[(wn * (BN / 2) + j * 16 + (lane & 15)) * 64 + kk + ((lane >> 4) << 3)];
      #pragma unroll
      for (int i = 0; i < FM; ++i)
        #pragma unroll
        for (int j = 0; j < FN; ++j)
          acc[i][j] = __builtin_amdgcn_mfma_f32_16x16x32_bf16(af[i], bfr[j], acc[i][j], 0, 0, 0);
    }
  }
  const int r4 = (lane >> 4) << 2;
  const int cc = lane & 15;
  #pragma unroll
  for (int i = 0; i < FM; ++i) {
    #pragma unroll
    for (int j = 0; j < FN; ++j) {
      const int row0 = m0 + wm * (BM / 2) + i * 16 + r4;
      const int col = n0 + wn * (BN / 2) + j * 16 + cc;
      float v[4];
      #pragma unroll
      for (int q = 0; q < 4; ++q) v[q] = acc[i][j][q];
      if (d.Cadd) {
        #pragma unroll
        for (int q = 0; q < 4; ++q) v[q] += bf2f(d.Cadd[(size_t)(row0 + q) * d.N + col]);
      }
      if (d.Fadd) {
        #pragma unroll
        for (int q = 0; q < 4; ++q) v[q] += d.Fadd[(size_t)(row0 + q) * d.N + col];
      }
      if (d.scale != 1.0f) {
        #pragma unroll
        for (int q = 0; q < 4; ++q) v[q] *= d.scale;
      }
      if (d.D) {
        #pragma unroll
        for (int q = 0; q < 4; ++q) d.D[(size_t)(row0 + q) * d.N + col] = f2bf(v[q]);
      }
      if (d.Df) {
        #pragma unroll
        for (int q = 0; q < 4; ++q) d.Df[(size_t)(row0 + q) * d.N + col] = v[q];
      }
      if (d.Dt) {
        ushort4 pk = make_ushort4(f2bf(v[0]), f2bf(v[1]), f2bf(v[2]), f2bf(v[3]));
        *(ushort4*)&d.Dt[(size_t)col * d.M + row0] = pk;
      }
    }
  }
}

// read f32 [R][C]; write straight bf16 [R][C] and transposed bf16 [C][R]
__global__ __launch_bounds__(256) void conv_both(const float* in, u16* outs, u16* outt, int R, int C) {
  __shared__ float tile[64][65];
  int tiles_c = C >> 6;
  int tr = blockIdx.x / tiles_c;
  int tc = blockIdx.x - tr * tiles_c;
  int r0 = tr << 6, c0 = tc << 6;
  int lr = threadIdx.x >> 6, lc = threadIdx.x & 63;
  #pragma unroll
  for (int p = 0; p < 16; ++p) {
    int r = p * 4 + lr;
    float v = in[(size_t)(r0 + r) * C + c0 + lc];
    tile[r][lc] = v;
    outs[(size_t)(r0 + r) * C + c0 + lc] = f2bf(v);
  }
  __syncthreads();
  #pragma unroll
  for (int p = 0; p < 16; ++p) {
    int r = p * 4 + lr;
    outt[(size_t)(c0 + r) * R + r0 + lc] = f2bf(tile[lc][r]);
  }
}

// transposed-only bf16 convert
__global__ __launch_bounds__(256) void conv_t(const float* in, u16* out, int R, int C) {
  __shared__ float tile[64][65];
  int tiles_c = C >> 6;
  int tr = blockIdx.x / tiles_c;
  int tc = blockIdx.x - tr * tiles_c;
  int r0 = tr << 6, c0 = tc << 6;
  int lr = threadIdx.x >> 6, lc = threadIdx.x & 63;
  #pragma unroll
  for (int p = 0; p < 16; ++p) {
    int r = p * 4 + lr;
    tile[r][lc] = in[(size_t)(r0 + r) * C + c0 + lc];
  }
  __syncthreads();
  #pragma unroll
  for (int p = 0; p < 16; ++p) {
    int r = p * 4 + lr;
    out[(size_t)(c0 + r) * R + r0 + lc] = f2bf(tile[lc][r]);
  }
}

// stage 1: partial[rc][j] = sum of 32 rows; grid = 16 rowchunks x 8 colblocks
__global__ __launch_bounds__(256) void colsum1(const float* Cm, float* partial, int cols) {
  int rc = blockIdx.x >> 3;
  int j = (blockIdx.x & 7) * 256 + threadIdx.x;
  float s = 0.f;
  #pragma unroll 8
  for (int i = 0; i < 32; ++i) s += Cm[(size_t)(rc * 32 + i) * cols + j];
  partial[(size_t)rc * cols + j] = s;
}
// stage 2: v[j] = sum_rc partial[rc][j]
__global__ __launch_bounds__(256) void colsum2(const float* partial, float* v, int cols) {
  int j = blockIdx.x * 256 + threadIdx.x;
  float s = 0.f;
  #pragma unroll
  for (int rc = 0; rc < 16; ++rc) s += partial[(size_t)rc * cols + j];
  v[j] = s;
}

// tout = tin + M @ tin ; M bf16 [n][n] row-major
__global__ __launch_bounds__(256) void matvec_add(const u16* Mtx, const float* tin, float* tout, int n) {
  __shared__ float ts[2048];
  for (int i = threadIdx.x; i < n; i += 256) ts[i] = tin[i];
  __syncthreads();
  int w = threadIdx.x >> 6, lane = threadIdx.x & 63;
  int row = blockIdx.x * 4 + w;
  float s = 0.f;
  for (int k0 = lane * 8; k0 < n; k0 += 512) {
    bf16x8 mv = *(const bf16x8*)&Mtx[(size_t)row * n + k0];
    #pragma unroll
    for (int e = 0; e < 8; ++e) s += bf2f((u16)mv[e]) * ts[k0 + e];
  }
  #pragma unroll
  for (int off = 32; off > 0; off >>= 1) s += __shfl_down(s, off);
  if (lane == 0) tout[row] = ts[row] + s;
}

// u[row] = dot(Cm[row], t) ; Cm f32 [rows][n]
__global__ __launch_bounds__(256) void matvec_f32(const float* Cm, const float* t, float* u, int rows, int n) {
  __shared__ float ts[2048];
  for (int i = threadIdx.x; i < n; i += 256) ts[i] = t[i];
  __syncthreads();
  int w = threadIdx.x >> 6, lane = threadIdx.x & 63;
  int row = blockIdx.x * 4 + w;
  if (row >= rows) return;
  float s = 0.f;
  for (int k0 = lane * 4; k0 < n; k0 += 256) {
    float4 c4 = *(const float4*)&Cm[(size_t)row * n + k0];
    s += c4.x * ts[k0] + c4.y * ts[k0 + 1] + c4.z * ts[k0 + 2] + c4.w * ts[k0 + 3];
  }
  #pragma unroll
  for (int off = 32; off > 0; off >>= 1) s += __shfl_down(s, off);
  if (lane == 0) u[row] = s;
}

__global__ __launch_bounds__(256) void dhat_k(const float* DF, const float* u, float* out) {
  int idx = blockIdx.x * 256 + threadIdx.x;
  int i = idx >> 9;
  out[idx] = 0.5f * (1.0f - u[i]) * (1.0f / 512.0f) + 0.5f * DF[idx];
}

extern "C" void kernel_launch(void* const* d_in, const int* in_sizes, int n_in,
                              void* d_out, int out_size, void* d_ws, size_t ws_size,
                              hipStream_t stream) {
  (void)in_sizes; (void)n_in; (void)out_size; (void)ws_size;
  const float* Cf  = (const float*)d_in[0];  // [512][2048]
  const float* Af  = (const float*)d_in[1];  // [2048][2048]
  const float* AFf = (const float*)d_in[2];  // [2048][2048]
  const float* BFf = (const float*)d_in[3];  // [2048][512]
  const float* CFf = (const float*)d_in[4];  // [512][2048]
  const float* DFf = (const float*)d_in[5];  // [512][512]
  float* out = (float*)d_out;                // B_hat [2048][512] ++ D_hat [512][512]

  const size_t SLOT = 2048ull * 2048ull * 2ull;  // 8 MiB
  char* ws = (char*)d_ws;
  auto slot = [&](int i) { return (u16*)(ws + (size_t)i * SLOT); };
  // M = A^T (row form), N = A_F (row form)
  u16* Mb  = slot(0);   // M
  u16* MbT = slot(1);   // M^T = A
  u16* MA  = slot(2);   // M1 = M^2
  u16* MTA = slot(3);   // M1^T
  u16* MB_ = slot(4);   // M2 = M^4
  u16* Nb  = slot(5);   // N
  u16* NbT = slot(6);   // N^T
  u16* NA  = slot(7);   // N1
  u16* NTA = slot(8);   // N1^T
  u16* NB_ = slot(9);   // N2
  u16* SA  = slot(10);  // X, later S2
  u16* SB  = slot(11);  // S1
  u16* STx = slot(12);  // X^T, later S1^T
  u16* Tb  = slot(13);  // T0, later T1
  char* sk = ws + 14 * SLOT;
  u16* CtB = (u16*)(sk + (0ull << 20));    // C^T   [2048][512]
  u16* CFT = (u16*)(sk + (2ull << 20));    // C_F^T [2048][512]
  u16* BFT = (u16*)(sk + (4ull << 20));    // B_F^T [512][2048]
  u16* YT  = (u16*)(sk + (6ull << 20));    // (N2 B_F)^T [512][2048]
  u16* ZT  = (u16*)(sk + (8ull << 20));    // (S2 Y)^T   [512][2048]
  float* V0f = (float*)(sk + (10ull << 20)); // S2 B_F f32 [2048][512]
  float* part = (float*)(sk + (15ull << 20));
  float* vv = part + 16 * 2048;
  float* ta = vv + 4096;
  float* tb = ta + 4096;
  float* uu = tb + 4096;

  auto mk = [](const u16* A, const u16* Bt, const u16* Cadd, const float* Fadd,
               u16* D, u16* Dt, float* Df, int M, int N, int K, float scale, int bm, int bn) {
    GemmDesc g; g.A = A; g.Bt = Bt; g.Cadd = Cadd; g.Fadd = Fadd;
    g.D = D; g.Dt = Dt; g.Df = Df; g.M = M; g.N = N; g.K = K;
    g.tn = N / bn; g.tiles = (M / bm) * (N / bn); g.scale = scale; return g;
  };

  // ---- input conversion ----
  conv_both<<<1024, 256, 0, stream>>>(Af, MbT, Mb, 2048, 2048);   // straight A, transposed A^T=M
  conv_both<<<1024, 256, 0, stream>>>(AFf, Nb, NbT, 2048, 2048);  // straight N=A_F, transposed N^T
  conv_t<<<256, 256, 0, stream>>>(Cf, CtB, 512, 2048);
  conv_t<<<256, 256, 0, stream>>>(CFf, CFT, 512, 2048);
  conv_t<<<256, 256, 0, stream>>>(BFf, BFT, 2048, 512);
  colsum1<<<128, 256, 0, stream>>>(Cf, part, 2048);
  colsum2<<<8, 256, 0, stream>>>(part, vv, 2048);

  // ---- P0: M1 = M@M | N1 = N@N | X = C^T @ C_F (dual X, X^T) ----
  { GemmBatch gb{}; gb.nd = 3;
    gb.d[0] = mk(Mb, MbT, nullptr, nullptr, MA, MTA, nullptr, 2048, 2048, 2048, 1.f, 128, 128);
    gb.d[1] = mk(Nb, NbT, nullptr, nullptr, NA, NTA, nullptr, 2048, 2048, 2048, 1.f, 128, 128);
    gb.d[2] = mk(CtB, CFT, nullptr, nullptr, SA, STx, nullptr, 2048, 2048, 512, 1.f, 128, 128);
    gemm_bt<128, 128><<<768, 256, 0, stream>>>(gb); }
  matvec_add<<<512, 256, 0, stream>>>(Mb, vv, ta, 2048);   // t1 = v + M v
  // ---- P1: T0 = M@X | M2 = M1@M1 | N2 = N1@N1 ----
  { GemmBatch gb{}; gb.nd = 3;
    gb.d[0] = mk(Mb, STx, nullptr, nullptr, Tb, nullptr, nullptr, 2048, 2048, 2048, 1.f, 128, 128);
    gb.d[1] = mk(MA, MTA, nullptr, nullptr, MB_, nullptr, nullptr, 2048, 2048, 2048, 1.f, 128, 128);
    gb.d[2] = mk(NA, NTA, nullptr, nullptr, NB_, nullptr, nullptr, 2048, 2048, 2048, 1.f, 128, 128);
    gemm_bt<128, 128><<<768, 256, 0, stream>>>(gb); }
  matvec_add<<<512, 256, 0, stream>>>(MA, ta, tb, 2048);   // t2 = t1 + M1 t1
  // ---- P2: S1 = X + T0@N (dual S1, S1^T) — 128x64, 512 WG ----
  { GemmBatch gb{}; gb.nd = 1;
    gb.d[0] = mk(Tb, NbT, SA, nullptr, SB, STx, nullptr, 2048, 2048, 2048, 1.f, 128, 64);
    gemm_bt<128, 64><<<512, 256, 0, stream>>>(gb); }
  matvec_add<<<512, 256, 0, stream>>>(MB_, tb, ta, 2048);  // t3 = t2 + M2 t2  (= sum_{k<8} M^k v)
  // ---- P3: T1 = M1@S1 | Y = N2@B_F (write Y^T) — 128x64, 640 WG ----
  { GemmBatch gb{}; gb.nd = 2;
    gb.d[0] = mk(MA, STx, nullptr, nullptr, Tb, nullptr, nullptr, 2048, 2048, 2048, 1.f, 128, 64);
    gb.d[1] = mk(NB_, BFT, nullptr, nullptr, nullptr, YT, nullptr, 2048, 512, 2048, 1.f, 128, 64);
    gemm_bt<128, 64><<<640, 256, 0, stream>>>(gb); }
  // ---- P4: S2 = S1 + T1@N1 — 128x64, 512 WG ----
  { GemmBatch gb{}; gb.nd = 1;
    gb.d[0] = mk(Tb, NTA, SB, nullptr, SA, nullptr, nullptr, 2048, 2048, 2048, 1.f, 128, 64);
    gemm_bt<128, 64><<<512, 256, 0, stream>>>(gb); }
  // ---- P5: V0 = S2@B_F (f32) | Z = S2@Y (write Z^T) — 64x64, 512 WG ----
  { GemmBatch gb{}; gb.nd = 2;
    gb.d[0] = mk(SA, BFT, nullptr, nullptr, nullptr, nullptr, V0f, 2048, 512, 2048, 1.f, 64, 64);
    gb.d[1] = mk(SA, YT, nullptr, nullptr, nullptr, ZT, nullptr, 2048, 512, 2048, 1.f, 64, 64);
    gemm_bt<64, 64><<<512, 256, 0, stream>>>(gb); }
  // ---- P6: B_hat = -(M2@Z + V0) -> d_out f32 — 64x64, 256 WG ----
  { GemmBatch gb{}; gb.nd = 1;
    gb.d[0] = mk(MB_, ZT, nullptr, V0f, nullptr, nullptr, out, 2048, 512, 2048, -1.f, 64, 64);
    gemm_bt<64, 64><<<256, 256, 0, stream>>>(gb); }
  // ---- D_hat ----
  matvec_f32<<<128, 256, 0, stream>>>(Cf, ta, uu, 512, 2048);
  dhat_k<<<1024, 256, 0, stream>>>(DFf, uu, out + 2048 * 512);
}

// Round 3
// 342.762 us; speedup vs baseline: 1.7296x; 1.0448x over previous
//
#include <hip/hip_runtime.h>

typedef unsigned short u16;
typedef __attribute__((ext_vector_type(4))) float f32x4;
typedef __attribute__((ext_vector_type(8))) short bf16x8;

#define AS1 __attribute__((address_space(1)))
#define AS3 __attribute__((address_space(3)))

__device__ __forceinline__ float bf2f(u16 u) {
  union { unsigned int i; float f; } v; v.i = ((unsigned int)u) << 16; return v.f;
}
__device__ __forceinline__ u16 f2bf(float f) {
  union { float f; unsigned int i; } v; v.f = f;
  unsigned int r = v.i + 0x7fffu + ((v.i >> 16) & 1u);  // RNE
  return (u16)(r >> 16);
}
__device__ __forceinline__ void gload16(const void* g, void* l) {
  __builtin_amdgcn_global_load_lds((const AS1 unsigned int*)g, (AS3 unsigned int*)l, 16, 0, 0);
}

struct GemmDesc {
  const u16* A;     // [M][K] bf16 row-major
  const u16* Bt;    // [N][K] bf16 row-major (B transposed)
  const u16* Cadd;  // optional bf16 [M][N] addend
  const float* Fadd;// optional f32  [M][N] addend
  u16* D;           // optional bf16 [M][N] out
  u16* Dt;          // optional bf16 [N][M] out (transposed)
  float* Df;        // optional f32  [M][N] out
  int M, N, K, tn, tiles;
  float scale;
};
struct GemmBatch { GemmDesc d[4]; int nd; };

// D = A @ Bt^T (+adds), bf16 in, f32 acc. BMxBN tile, BK=64, 4 waves (2x2).
template<int BM, int BN>
__global__ __launch_bounds__(256) void gemm_bt(GemmBatch b) {
  const int nwg = gridDim.x;  // multiple of 8
  int t = ((blockIdx.x & 7) * (nwg >> 3)) + (blockIdx.x >> 3);
  int di = 0;
  while (di + 1 < b.nd && t >= b.d[di].tiles) { t -= b.d[di].tiles; ++di; }
  const GemmDesc d = b.d[di];
  const int tm = t / d.tn, tnn = t - tm * d.tn;
  const int m0 = tm * BM, n0 = tnn * BN;
  const int lane = threadIdx.x & 63;
  const int w = threadIdx.x >> 6;
  const int wm = w >> 1, wn = w & 1;
  constexpr int FM = BM / 32, FN = BN / 32;
  __shared__ __align__(16) u16 Asm[BM * 64];
  __shared__ __align__(16) u16 Bsm[BN * 64];
  f32x4 acc[FM][FN];
  #pragma unroll
  for (int i = 0; i < FM; ++i)
    #pragma unroll
    for (int j = 0; j < FN; ++j)
      acc[i][j] = (f32x4){0.f, 0.f, 0.f, 0.f};
  const int srow = lane >> 3, scol = (lane & 7) << 3;
  const int K = d.K;
  for (int k0 = 0; k0 < K; k0 += 64) {
    __syncthreads();
    #pragma unroll
    for (int c = w; c < BM / 8; c += 4)
      gload16(d.A + (size_t)(m0 + c * 8 + srow) * K + k0 + scol, &Asm[c * 512]);
    #pragma unroll
    for (int c = w; c < BN / 8; c += 4)
      gload16(d.Bt + (size_t)(n0 + c * 8 + srow) * K + k0 + scol, &Bsm[c * 512]);
    __syncthreads();
    #pragma unroll
    for (int kk = 0; kk < 64; kk += 32) {
      bf16x8 af[FM], bfr[FN];
      #pragma unroll
      for (int i = 0; i < FM; ++i)
        af[i] = *(const bf16x8*)&Asm[(wm * (BM / 2) + i * 16 + (lane & 15)) * 64 + kk + ((lane >> 4) << 3)];
      #pragma unroll
      for (int j = 0; j < FN; ++j)
        bfr[j] = *(const bf16x8*)&Bsm[(wn * (BN / 2) + j * 16 + (lane & 15)) * 64 + kk + ((lane >> 4) << 3)];
      #pragma unroll
      for (int i = 0; i < FM; ++i)
        #pragma unroll
        for (int j = 0; j < FN; ++j)
          acc[i][j] = __builtin_amdgcn_mfma_f32_16x16x32_bf16(af[i], bfr[j], acc[i][j], 0, 0, 0);
    }
  }
  const int r4 = (lane >> 4) << 2;
  const int cc = lane & 15;
  #pragma unroll
  for (int i = 0; i < FM; ++i) {
    #pragma unroll
    for (int j = 0; j < FN; ++j) {
      const int row0 = m0 + wm * (BM / 2) + i * 16 + r4;
      const int col = n0 + wn * (BN / 2) + j * 16 + cc;
      float v[4];
      #pragma unroll
      for (int q = 0; q < 4; ++q) v[q] = acc[i][j][q];
      if (d.Cadd) {
        #pragma unroll
        for (int q = 0; q < 4; ++q) v[q] += bf2f(d.Cadd[(size_t)(row0 + q) * d.N + col]);
      }
      if (d.Fadd) {
        #pragma unroll
        for (int q = 0; q < 4; ++q) v[q] += d.Fadd[(size_t)(row0 + q) * d.N + col];
      }
      if (d.scale != 1.0f) {
        #pragma unroll
        for (int q = 0; q < 4; ++q) v[q] *= d.scale;
      }
      if (d.D) {
        #pragma unroll
        for (int q = 0; q < 4; ++q) d.D[(size_t)(row0 + q) * d.N + col] = f2bf(v[q]);
      }
      if (d.Df) {
        #pragma unroll
        for (int q = 0; q < 4; ++q) d.Df[(size_t)(row0 + q) * d.N + col] = v[q];
      }
      if (d.Dt) {
        ushort4 pk = make_ushort4(f2bf(v[0]), f2bf(v[1]), f2bf(v[2]), f2bf(v[3]));
        *(ushort4*)&d.Dt[(size_t)col * d.M + row0] = pk;
      }
    }
  }
}

// read f32 [R][C]; write straight bf16 [R][C] and transposed bf16 [C][R]
__global__ __launch_bounds__(256) void conv_both(const float* in, u16* outs, u16* outt, int R, int C) {
  __shared__ float tile[64][65];
  int tiles_c = C >> 6;
  int tr = blockIdx.x / tiles_c;
  int tc = blockIdx.x - tr * tiles_c;
  int r0 = tr << 6, c0 = tc << 6;
  int lr = threadIdx.x >> 6, lc = threadIdx.x & 63;
  #pragma unroll
  for (int p = 0; p < 16; ++p) {
    int r = p * 4 + lr;
    float v = in[(size_t)(r0 + r) * C + c0 + lc];
    tile[r][lc] = v;
    outs[(size_t)(r0 + r) * C + c0 + lc] = f2bf(v);
  }
  __syncthreads();
  #pragma unroll
  for (int p = 0; p < 16; ++p) {
    int r = p * 4 + lr;
    outt[(size_t)(c0 + r) * R + r0 + lc] = f2bf(tile[lc][r]);
  }
}

// transposed-only bf16 convert
__global__ __launch_bounds__(256) void conv_t(const float* in, u16* out, int R, int C) {
  __shared__ float tile[64][65];
  int tiles_c = C >> 6;
  int tr = blockIdx.x / tiles_c;
  int tc = blockIdx.x - tr * tiles_c;
  int r0 = tr << 6, c0 = tc << 6;
  int lr = threadIdx.x >> 6, lc = threadIdx.x & 63;
  #pragma unroll
  for (int p = 0; p < 16; ++p) {
    int r = p * 4 + lr;
    tile[r][lc] = in[(size_t)(r0 + r) * C + c0 + lc];
  }
  __syncthreads();
  #pragma unroll
  for (int p = 0; p < 16; ++p) {
    int r = p * 4 + lr;
    out[(size_t)(c0 + r) * R + r0 + lc] = f2bf(tile[lc][r]);
  }
}

// stage 1: partial[rc][j] = sum of 32 rows; grid = 16 rowchunks x 8 colblocks
__global__ __launch_bounds__(256) void colsum1(const float* Cm, float* partial, int cols) {
  int rc = blockIdx.x >> 3;
  int j = (blockIdx.x & 7) * 256 + threadIdx.x;
  float s = 0.f;
  #pragma unroll 8
  for (int i = 0; i < 32; ++i) s += Cm[(size_t)(rc * 32 + i) * cols + j];
  partial[(size_t)rc * cols + j] = s;
}
// stage 2: v[j] = sum_rc partial[rc][j]
__global__ __launch_bounds__(256) void colsum2(const float* partial, float* v, int cols) {
  int j = blockIdx.x * 256 + threadIdx.x;
  float s = 0.f;
  #pragma unroll
  for (int rc = 0; rc < 16; ++rc) s += partial[(size_t)rc * cols + j];
  v[j] = s;
}

// tout = tadd + Mtx @ tmul ; Mtx bf16 [n][n] row-major
__global__ __launch_bounds__(256) void matvec_h(const u16* Mtx, const float* tmul,
                                                const float* tadd, float* tout, int n) {
  __shared__ float ts[2048];
  for (int i = threadIdx.x; i < n; i += 256) ts[i] = tmul[i];
  __syncthreads();
  int w = threadIdx.x >> 6, lane = threadIdx.x & 63;
  int row = blockIdx.x * 4 + w;
  float s = 0.f;
  for (int k0 = lane * 8; k0 < n; k0 += 512) {
    bf16x8 mv = *(const bf16x8*)&Mtx[(size_t)row * n + k0];
    #pragma unroll
    for (int e = 0; e < 8; ++e) s += bf2f((u16)mv[e]) * ts[k0 + e];
  }
  #pragma unroll
  for (int off = 32; off > 0; off >>= 1) s += __shfl_down(s, off);
  if (lane == 0) tout[row] = tadd[row] + s;
}

// u[row] = dot(Cm[row], t) ; Cm f32 [rows][n]
__global__ __launch_bounds__(256) void matvec_f32(const float* Cm, const float* t, float* u, int rows, int n) {
  __shared__ float ts[2048];
  for (int i = threadIdx.x; i < n; i += 256) ts[i] = t[i];
  __syncthreads();
  int w = threadIdx.x >> 6, lane = threadIdx.x & 63;
  int row = blockIdx.x * 4 + w;
  if (row >= rows) return;
  float s = 0.f;
  for (int k0 = lane * 4; k0 < n; k0 += 256) {
    float4 c4 = *(const float4*)&Cm[(size_t)row * n + k0];
    s += c4.x * ts[k0] + c4.y * ts[k0 + 1] + c4.z * ts[k0 + 2] + c4.w * ts[k0 + 3];
  }
  #pragma unroll
  for (int off = 32; off > 0; off >>= 1) s += __shfl_down(s, off);
  if (lane == 0) u[row] = s;
}

__global__ __launch_bounds__(256) void dhat_k(const float* DF, const float* u, float* out) {
  int idx = blockIdx.x * 256 + threadIdx.x;
  int i = idx >> 9;
  out[idx] = 0.5f * (1.0f - u[i]) * (1.0f / 512.0f) + 0.5f * DF[idx];
}

extern "C" void kernel_launch(void* const* d_in, const int* in_sizes, int n_in,
                              void* d_out, int out_size, void* d_ws, size_t ws_size,
                              hipStream_t stream) {
  (void)in_sizes; (void)n_in; (void)out_size; (void)ws_size;
  const float* Cf  = (const float*)d_in[0];  // [512][2048]
  const float* Af  = (const float*)d_in[1];  // [2048][2048]
  const float* AFf = (const float*)d_in[2];  // [2048][2048]
  const float* BFf = (const float*)d_in[3];  // [2048][512]
  const float* CFf = (const float*)d_in[4];  // [512][2048]
  const float* DFf = (const float*)d_in[5];  // [512][512]
  float* out = (float*)d_out;                // B_hat [2048][512] ++ D_hat [512][512]

  const size_t SLOT = 2048ull * 2048ull * 2ull;  // 8 MiB
  char* ws = (char*)d_ws;
  auto slot = [&](int i) { return (u16*)(ws + (size_t)i * SLOT); };
  // M = A^T (row form), N = A_F (row form)
  u16* Mb  = slot(0);   // M
  u16* MbT = slot(1);   // M^T = A  (Bt-form of M)
  u16* MA  = slot(2);   // M1 = M^2
  u16* Nb  = slot(3);   // N
  u16* NbT = slot(4);   // N^T
  u16* NA  = slot(5);   // N1 = N^2
  u16* SA  = slot(6);   // X
  u16* STx = slot(7);   // X^T
  u16* Tb  = slot(8);   // T0 = M@X
  u16* S2b = slot(9);   // S2 = X + T0@N
  char* sk = ws + 10 * SLOT;
  u16* CtB = (u16*)(sk + (0ull << 20));    // C^T   [2048][512]
  u16* CFT = (u16*)(sk + (2ull << 20));    // C_F^T [2048][512]
  u16* BFT = (u16*)(sk + (4ull << 20));    // B_F^T [512][2048]
  u16* Y1T = (u16*)(sk + (6ull << 20));    // (N1 B_F)^T   [512][2048]
  u16* Y2T = (u16*)(sk + (8ull << 20));    // (N1^2 B_F)^T
  u16* Y3T = (u16*)(sk + (10ull << 20));   // (N1^3 B_F)^T
  u16* G3T = (u16*)(sk + (12ull << 20));   // (S2 Y3)^T
  u16* H2T = (u16*)(sk + (14ull << 20));   // (G2 + M1 G3)^T
  u16* H1T = (u16*)(sk + (16ull << 20));   // (G1 + M1 H2)^T
  float* G0f = (float*)(sk + (18ull << 20)); // S2 B_F   f32 [2048][512]
  float* G1f = (float*)(sk + (22ull << 20)); // S2 Y1    f32
  float* G2f = (float*)(sk + (26ull << 20)); // S2 Y2    f32
  float* part = (float*)(sk + (30ull << 20));
  float* vv = part + 16 * 2048;
  float* ta = vv + 4096;
  float* tb = ta + 4096;
  float* tc = tb + 4096;
  float* td = tc + 4096;
  float* uu = td + 4096;

  auto mk = [](const u16* A, const u16* Bt, const u16* Cadd, const float* Fadd,
               u16* D, u16* Dt, float* Df, int M, int N, int K, float scale, int bm, int bn) {
    GemmDesc g; g.A = A; g.Bt = Bt; g.Cadd = Cadd; g.Fadd = Fadd;
    g.D = D; g.Dt = Dt; g.Df = Df; g.M = M; g.N = N; g.K = K;
    g.tn = N / bn; g.tiles = (M / bm) * (N / bn); g.scale = scale; return g;
  };

  // ---- input conversion ----
  conv_both<<<1024, 256, 0, stream>>>(Af, MbT, Mb, 2048, 2048);   // MbT = A, Mb = A^T = M
  conv_both<<<1024, 256, 0, stream>>>(AFf, Nb, NbT, 2048, 2048);  // Nb = A_F = N, NbT = N^T
  conv_t<<<256, 256, 0, stream>>>(Cf, CtB, 512, 2048);
  conv_t<<<256, 256, 0, stream>>>(CFf, CFT, 512, 2048);
  conv_t<<<256, 256, 0, stream>>>(BFf, BFT, 2048, 512);
  colsum1<<<128, 256, 0, stream>>>(Cf, part, 2048);
  colsum2<<<8, 256, 0, stream>>>(part, vv, 2048);
  matvec_h<<<512, 256, 0, stream>>>(Mb, vv, vv, ta, 2048);        // ta = (I+M)v

  // ---- P0: M1 = M@M | N1 = N@N | X = C^T @ C_F (dual X, X^T) ----
  { GemmBatch gb{}; gb.nd = 3;
    gb.d[0] = mk(Mb, MbT, nullptr, nullptr, MA, nullptr, nullptr, 2048, 2048, 2048, 1.f, 128, 128);
    gb.d[1] = mk(Nb, NbT, nullptr, nullptr, NA, nullptr, nullptr, 2048, 2048, 2048, 1.f, 128, 128);
    gb.d[2] = mk(CtB, CFT, nullptr, nullptr, SA, STx, nullptr, 2048, 2048, 512, 1.f, 128, 128);
    gemm_bt<128, 128><<<768, 256, 0, stream>>>(gb); }
  // t-vector Horner with M1: td = sum_{k<8} M^k v
  matvec_h<<<512, 256, 0, stream>>>(MA, ta, ta, tb, 2048);        // tb = ta + M1 ta
  matvec_h<<<512, 256, 0, stream>>>(MA, tb, ta, tc, 2048);        // tc = ta + M1 tb
  matvec_h<<<512, 256, 0, stream>>>(MA, tc, ta, td, 2048);        // td = ta + M1 tc

  // ---- P1: T0 = M@X | Y1 = N1@B_F (write Y1^T) — 128x64, 640 WG ----
  { GemmBatch gb{}; gb.nd = 2;
    gb.d[0] = mk(Mb, STx, nullptr, nullptr, Tb, nullptr, nullptr, 2048, 2048, 2048, 1.f, 128, 64);
    gb.d[1] = mk(NA, BFT, nullptr, nullptr, nullptr, Y1T, nullptr, 2048, 512, 2048, 1.f, 128, 64);
    gemm_bt<128, 64><<<640, 256, 0, stream>>>(gb); }
  // ---- P2: S2 = X + T0@N | Y2 = N1@Y1 (write Y2^T) — 128x64, 640 WG ----
  { GemmBatch gb{}; gb.nd = 2;
    gb.d[0] = mk(Tb, NbT, SA, nullptr, S2b, nullptr, nullptr, 2048, 2048, 2048, 1.f, 128, 64);
    gb.d[1] = mk(NA, Y1T, nullptr, nullptr, nullptr, Y2T, nullptr, 2048, 512, 2048, 1.f, 128, 64);
    gemm_bt<128, 64><<<640, 256, 0, stream>>>(gb); }
  // ---- P3: Y3 = N1@Y2 | G0 = S2@B_F | G1 = S2@Y1 | G2 = S2@Y2 — 128x64, 512 WG ----
  { GemmBatch gb{}; gb.nd = 4;
    gb.d[0] = mk(NA, Y2T, nullptr, nullptr, nullptr, Y3T, nullptr, 2048, 512, 2048, 1.f, 128, 64);
    gb.d[1] = mk(S2b, BFT, nullptr, nullptr, nullptr, nullptr, G0f, 2048, 512, 2048, 1.f, 128, 64);
    gb.d[2] = mk(S2b, Y1T, nullptr, nullptr, nullptr, nullptr, G1f, 2048, 512, 2048, 1.f, 128, 64);
    gb.d[3] = mk(S2b, Y2T, nullptr, nullptr, nullptr, nullptr, G2f, 2048, 512, 2048, 1.f, 128, 64);
    gemm_bt<128, 64><<<512, 256, 0, stream>>>(gb); }
  // ---- P4: G3 = S2@Y3 (write G3^T) — 64x64, 256 WG ----
  { GemmBatch gb{}; gb.nd = 1;
    gb.d[0] = mk(S2b, Y3T, nullptr, nullptr, nullptr, G3T, nullptr, 2048, 512, 2048, 1.f, 64, 64);
    gemm_bt<64, 64><<<256, 256, 0, stream>>>(gb); }
  // ---- P5: H2 = G2 + M1@G3 (write H2^T) ----
  { GemmBatch gb{}; gb.nd = 1;
    gb.d[0] = mk(MA, G3T, nullptr, G2f, nullptr, H2T, nullptr, 2048, 512, 2048, 1.f, 64, 64);
    gemm_bt<64, 64><<<256, 256, 0, stream>>>(gb); }
  // ---- P6: H1 = G1 + M1@H2 (write H1^T) ----
  { GemmBatch gb{}; gb.nd = 1;
    gb.d[0] = mk(MA, H2T, nullptr, G1f, nullptr, H1T, nullptr, 2048, 512, 2048, 1.f, 64, 64);
    gemm_bt<64, 64><<<256, 256, 0, stream>>>(gb); }
  // ---- P7: B_hat = -(G0 + M1@H1) -> d_out f32 ----
  { GemmBatch gb{}; gb.nd = 1;
    gb.d[0] = mk(MA, H1T, nullptr, G0f, nullptr, nullptr, out, 2048, 512, 2048, -1.f, 64, 64);
    gemm_bt<64, 64><<<256, 256, 0, stream>>>(gb); }
  // ---- D_hat ----
  matvec_f32<<<128, 256, 0, stream>>>(Cf, td, uu, 512, 2048);
  dhat_k<<<1024, 256, 0, stream>>>(DFf, uu, out + 2048 * 512);
}

// Round 4
// 302.069 us; speedup vs baseline: 1.9626x; 1.1347x over previous
//
#include <hip/hip_runtime.h>

typedef unsigned short u16;
typedef __attribute__((ext_vector_type(4))) float f32x4;
typedef __attribute__((ext_vector_type(8))) short bf16x8;

#define AS1 __attribute__((address_space(1)))
#define AS3 __attribute__((address_space(3)))

__device__ __forceinline__ float bf2f(u16 u) {
  union { unsigned int i; float f; } v; v.i = ((unsigned int)u) << 16; return v.f;
}
__device__ __forceinline__ u16 f2bf(float f) {
  union { float f; unsigned int i; } v; v.f = f;
  unsigned int r = v.i + 0x7fffu + ((v.i >> 16) & 1u);  // RNE
  return (u16)(r >> 16);
}
__device__ __forceinline__ void gload16(const void* g, void* l) {
  __builtin_amdgcn_global_load_lds((const AS1 unsigned int*)g, (AS3 unsigned int*)l, 16, 0, 0);
}

struct GemmDesc {
  const u16* A;      // [M][K] bf16, row stride lda
  const u16* Bt;     // [N][K] bf16, row stride ldb (B transposed)
  const float* Fadd; // optional f32 [M][N] addend (stride N)
  u16* D;            // optional bf16 out, row stride ldd
  u16* Dt;           // optional bf16 transposed out [N][M], row stride lddt
  float* Df;         // optional f32 out, row stride ldd
  int M, N, K, lda, ldb, ldd, lddt, tn, tiles;
  float scale;
};
struct GemmBatch { GemmDesc d[4]; int nd; };

// D = scale*(A @ Bt^T + Fadd), bf16 in, f32 acc. BMxBN tile, BK=64, 4 waves.
template<int BM, int BN>
__global__ __launch_bounds__(256) void gemm_bt(GemmBatch b) {
  const int nwg = gridDim.x;  // multiple of 8
  int t = ((blockIdx.x & 7) * (nwg >> 3)) + (blockIdx.x >> 3);
  int di = 0;
  while (di + 1 < b.nd && t >= b.d[di].tiles) { t -= b.d[di].tiles; ++di; }
  const GemmDesc d = b.d[di];
  const int tm = t / d.tn, tnn = t - tm * d.tn;
  const int m0 = tm * BM, n0 = tnn * BN;
  const int lane = threadIdx.x & 63;
  const int w = threadIdx.x >> 6;
  const int wm = w >> 1, wn = w & 1;
  constexpr int FM = BM / 32, FN = BN / 32;
  __shared__ __align__(16) u16 Asm[BM * 64];
  __shared__ __align__(16) u16 Bsm[BN * 64];
  f32x4 acc[FM][FN];
  #pragma unroll
  for (int i = 0; i < FM; ++i)
    #pragma unroll
    for (int j = 0; j < FN; ++j)
      acc[i][j] = (f32x4){0.f, 0.f, 0.f, 0.f};
  const int srow = lane >> 3, scol = (lane & 7) << 3;
  const int K = d.K;
  for (int k0 = 0; k0 < K; k0 += 64) {
    __syncthreads();
    #pragma unroll
    for (int c = w; c < BM / 8; c += 4)
      gload16(d.A + (size_t)(m0 + c * 8 + srow) * d.lda + k0 + scol, &Asm[c * 512]);
    #pragma unroll
    for (int c = w; c < BN / 8; c += 4)
      gload16(d.Bt + (size_t)(n0 + c * 8 + srow) * d.ldb + k0 + scol, &Bsm[c * 512]);
    __syncthreads();
    #pragma unroll
    for (int kk = 0; kk < 64; kk += 32) {
      bf16x8 af[FM], bfr[FN];
      #pragma unroll
      for (int i = 0; i < FM; ++i)
        af[i] = *(const bf16x8*)&Asm[(wm * (BM / 2) + i * 16 + (lane & 15)) * 64 + kk + ((lane >> 4) << 3)];
      #pragma unroll
      for (int j = 0; j < FN; ++j)
        bfr[j] = *(const bf16x8*)&Bsm[(wn * (BN / 2) + j * 16 + (lane & 15)) * 64 + kk + ((lane >> 4) << 3)];
      #pragma unroll
      for (int i = 0; i < FM; ++i)
        #pragma unroll
        for (int j = 0; j < FN; ++j)
          acc[i][j] = __builtin_amdgcn_mfma_f32_16x16x32_bf16(af[i], bfr[j], acc[i][j], 0, 0, 0);
    }
  }
  const int r4 = (lane >> 4) << 2;
  const int cc = lane & 15;
  #pragma unroll
  for (int i = 0; i < FM; ++i) {
    #pragma unroll
    for (int j = 0; j < FN; ++j) {
      const int row0 = m0 + wm * (BM / 2) + i * 16 + r4;
      const int col = n0 + wn * (BN / 2) + j * 16 + cc;
      float v[4];
      #pragma unroll
      for (int q = 0; q < 4; ++q) v[q] = acc[i][j][q];
      if (d.Fadd) {
        #pragma unroll
        for (int q = 0; q < 4; ++q) v[q] += d.Fadd[(size_t)(row0 + q) * d.N + col];
      }
      if (d.scale != 1.0f) {
        #pragma unroll
        for (int q = 0; q < 4; ++q) v[q] *= d.scale;
      }
      if (d.D) {
        #pragma unroll
        for (int q = 0; q < 4; ++q) d.D[(size_t)(row0 + q) * d.ldd + col] = f2bf(v[q]);
      }
      if (d.Df) {
        #pragma unroll
        for (int q = 0; q < 4; ++q) d.Df[(size_t)(row0 + q) * d.ldd + col] = v[q];
      }
      if (d.Dt) {
        ushort4 pk = make_ushort4(f2bf(v[0]), f2bf(v[1]), f2bf(v[2]), f2bf(v[3]));
        *(ushort4*)&d.Dt[(size_t)col * d.lddt + row0] = pk;
      }
    }
  }
}

// read f32 [R][C]; write straight bf16 [R][C] and transposed bf16 [C][R] (row stride ldt)
__global__ __launch_bounds__(256) void conv_both(const float* in, u16* outs, u16* outt, int R, int C, int ldt) {
  __shared__ float tile[64][65];
  int tiles_c = C >> 6;
  int tr = blockIdx.x / tiles_c;
  int tc = blockIdx.x - tr * tiles_c;
  int r0 = tr << 6, c0 = tc << 6;
  int lr = threadIdx.x >> 6, lc = threadIdx.x & 63;
  #pragma unroll
  for (int p = 0; p < 16; ++p) {
    int r = p * 4 + lr;
    float v = in[(size_t)(r0 + r) * C + c0 + lc];
    tile[r][lc] = v;
    outs[(size_t)(r0 + r) * C + c0 + lc] = f2bf(v);
  }
  __syncthreads();
  #pragma unroll
  for (int p = 0; p < 16; ++p) {
    int r = p * 4 + lr;
    outt[(size_t)(c0 + r) * ldt + r0 + lc] = f2bf(tile[lc][r]);
  }
}

// transposed-only bf16 convert: out [C][R]
__global__ __launch_bounds__(256) void conv_t(const float* in, u16* out, int R, int C) {
  __shared__ float tile[64][65];
  int tiles_c = C >> 6;
  int tr = blockIdx.x / tiles_c;
  int tc = blockIdx.x - tr * tiles_c;
  int r0 = tr << 6, c0 = tc << 6;
  int lr = threadIdx.x >> 6, lc = threadIdx.x & 63;
  #pragma unroll
  for (int p = 0; p < 16; ++p) {
    int r = p * 4 + lr;
    tile[r][lc] = in[(size_t)(r0 + r) * C + c0 + lc];
  }
  __syncthreads();
  #pragma unroll
  for (int p = 0; p < 16; ++p) {
    int r = p * 4 + lr;
    out[(size_t)(c0 + r) * R + r0 + lc] = f2bf(tile[lc][r]);
  }
}

// f32 -> bf16 straight (n4 = n/4)
__global__ __launch_bounds__(256) void conv_s(const float* in, u16* out, int n4) {
  int idx = blockIdx.x * 256 + threadIdx.x;
  int stride = gridDim.x * 256;
  for (int i = idx; i < n4; i += stride) {
    float4 f = ((const float4*)in)[i];
    ushort4 o = make_ushort4(f2bf(f.x), f2bf(f.y), f2bf(f.z), f2bf(f.w));
    ((ushort4*)out)[i] = o;
  }
}

// stage 1: partial[rc][j] = sum of 32 rows; grid = 16 rowchunks x 8 colblocks
__global__ __launch_bounds__(256) void colsum1(const float* Cm, float* partial, int cols) {
  int rc = blockIdx.x >> 3;
  int j = (blockIdx.x & 7) * 256 + threadIdx.x;
  float s = 0.f;
  #pragma unroll 8
  for (int i = 0; i < 32; ++i) s += Cm[(size_t)(rc * 32 + i) * cols + j];
  partial[(size_t)rc * cols + j] = s;
}
__global__ __launch_bounds__(256) void colsum2(const float* partial, float* v, int cols) {
  int j = blockIdx.x * 256 + threadIdx.x;
  float s = 0.f;
  #pragma unroll
  for (int rc = 0; rc < 16; ++rc) s += partial[(size_t)rc * cols + j];
  v[j] = s;
}

// tout = tadd + Mtx @ tmul ; Mtx bf16 [n][n] row-major
__global__ __launch_bounds__(256) void matvec_h(const u16* Mtx, const float* tmul,
                                                const float* tadd, float* tout, int n) {
  __shared__ float ts[2048];
  for (int i = threadIdx.x; i < n; i += 256) ts[i] = tmul[i];
  __syncthreads();
  int w = threadIdx.x >> 6, lane = threadIdx.x & 63;
  int row = blockIdx.x * 4 + w;
  float s = 0.f;
  for (int k0 = lane * 8; k0 < n; k0 += 512) {
    bf16x8 mv = *(const bf16x8*)&Mtx[(size_t)row * n + k0];
    #pragma unroll
    for (int e = 0; e < 8; ++e) s += bf2f((u16)mv[e]) * ts[k0 + e];
  }
  #pragma unroll
  for (int off = 32; off > 0; off >>= 1) s += __shfl_down(s, off);
  if (lane == 0) tout[row] = tadd[row] + s;
}

// u[row] = dot(Cm[row], t) ; Cm f32 [rows][n]
__global__ __launch_bounds__(256) void matvec_f32(const float* Cm, const float* t, float* u, int rows, int n) {
  __shared__ float ts[2048];
  for (int i = threadIdx.x; i < n; i += 256) ts[i] = t[i];
  __syncthreads();
  int w = threadIdx.x >> 6, lane = threadIdx.x & 63;
  int row = blockIdx.x * 4 + w;
  if (row >= rows) return;
  float s = 0.f;
  for (int k0 = lane * 4; k0 < n; k0 += 256) {
    float4 c4 = *(const float4*)&Cm[(size_t)row * n + k0];
    s += c4.x * ts[k0] + c4.y * ts[k0 + 1] + c4.z * ts[k0 + 2] + c4.w * ts[k0 + 3];
  }
  #pragma unroll
  for (int off = 32; off > 0; off >>= 1) s += __shfl_down(s, off);
  if (lane == 0) u[row] = s;
}

__global__ __launch_bounds__(256) void dhat_k(const float* DF, const float* u, float* out) {
  int idx = blockIdx.x * 256 + threadIdx.x;
  int i = idx >> 9;
  out[idx] = 0.5f * (1.0f - u[i]) * (1.0f / 512.0f) + 0.5f * DF[idx];
}

extern "C" void kernel_launch(void* const* d_in, const int* in_sizes, int n_in,
                              void* d_out, int out_size, void* d_ws, size_t ws_size,
                              hipStream_t stream) {
  (void)in_sizes; (void)n_in; (void)out_size; (void)ws_size;
  const float* Cf  = (const float*)d_in[0];  // [512][2048]
  const float* Af  = (const float*)d_in[1];  // [2048][2048]
  const float* AFf = (const float*)d_in[2];  // [2048][2048]
  const float* BFf = (const float*)d_in[3];  // [2048][512]
  const float* CFf = (const float*)d_in[4];  // [512][2048]
  const float* DFf = (const float*)d_in[5];  // [512][512]
  float* out = (float*)d_out;                // B_hat [2048][512] ++ D_hat [512][512]

  const size_t SLOT = 2048ull * 2048ull;     // elements (8 MiB as u16)
  char* ws = (char*)d_ws;
  auto slot = [&](int i) { return (u16*)(ws + (size_t)i * SLOT * 2); };
  // M = A^T, N = A_F
  u16* Mb   = slot(0);   // M straight
  u16* MbT  = slot(1);   // M^T = A straight
  u16* Nb   = slot(2);   // N straight
  u16* NbT  = slot(3);   // N^T straight
  u16* M2   = slot(4);   // M^2
  u16* M2T  = slot(5);   // (M^2)^T
  u16* M4   = slot(6);   // M^4
  u16* N2   = slot(7);   // N^2
  u16* N2T  = slot(8);   // (N^2)^T
  u16* KP   = slot(9);   // [P0|P1|P2|P3] col-blocks of 512, P_k = M^k C^T
  u16* Rcat = slot(10);  // rows: [R0;R1;R2;R3], R_k = C_F N^k  [2048][2048]
  char* sk = ws + 11 * SLOT * 2;
  u16* Cb   = (u16*)sk;                      // C straight bf16 [512][2048] (= P0^T, chain Bt)
  u16* PT1  = Cb + 512 * 2048;               // P1^T [512][2048] (contiguous after Cb: [Cb;PT1] stack)
  u16* BFT  = PT1 + 512 * 2048;              // B_F^T [512][2048]
  u16* YHT  = BFT + 512 * 2048;              // (N^2 B_F)^T
  u16* YT   = YHT + 512 * 2048;              // (N^4 B_F)^T
  u16* WT   = YT + 512 * 2048;               // Wcat^T  [512][2048]
  u16* W2T  = WT + 512 * 2048;               // W'cat^T [512][2048]
  u16* ZT   = W2T + 512 * 2048;              // Z^T     [512][2048]
  float* Vf = (float*)(ZT + 512 * 2048);     // V f32 [2048][512]
  float* part = Vf + 2048 * 512;
  float* vv = part + 16 * 2048;
  float* ta = vv + 4096;
  float* tb = ta + 4096;
  float* tc = tb + 4096;
  float* td = tc + 4096;
  float* uu = td + 4096;

  auto mk = [](const u16* A, int lda, const u16* Bt, int ldb, const float* Fadd,
               u16* D, u16* Dt, float* Df, int ldd, int lddt,
               int M, int N, int K, float scale, int bm, int bn) {
    GemmDesc g; g.A = A; g.Bt = Bt; g.Fadd = Fadd; g.D = D; g.Dt = Dt; g.Df = Df;
    g.M = M; g.N = N; g.K = K; g.lda = lda; g.ldb = ldb; g.ldd = ldd; g.lddt = lddt;
    g.tn = N / bn; g.tiles = (M / bm) * (N / bn); g.scale = scale; return g;
  };

  // ---- conversions ----
  conv_both<<<1024, 256, 0, stream>>>(Af, MbT, Mb, 2048, 2048, 2048);   // MbT=A, Mb=A^T=M
  conv_both<<<1024, 256, 0, stream>>>(AFf, Nb, NbT, 2048, 2048, 2048);  // Nb=N, NbT=N^T
  conv_both<<<256, 256, 0, stream>>>(Cf, Cb, KP, 512, 2048, 2048);      // Cb=C, KP col0 = C^T (ldt 2048)
  conv_s<<<1024, 256, 0, stream>>>(CFf, Rcat, (512 * 2048) / 4);        // Rcat row-block 0 = C_F = R0
  conv_t<<<256, 256, 0, stream>>>(BFf, BFT, 2048, 512);                 // BFT = B_F^T
  colsum1<<<128, 256, 0, stream>>>(Cf, part, 2048);
  colsum2<<<8, 256, 0, stream>>>(part, vv, 2048);
  matvec_h<<<512, 256, 0, stream>>>(Mb, vv, vv, ta, 2048);              // ta = (I+M)v

  // ---- G1: M2 = M@M (dual) | N2 = N@N (dual) | P1 = M@C^T (dual: KP col1 + PT1) | Q1: R1 = (N^T@R0^T)^T ----
  { GemmBatch gb{}; gb.nd = 4;
    gb.d[0] = mk(Mb, 2048, MbT, 2048, nullptr, M2, M2T, nullptr, 2048, 2048, 2048, 2048, 2048, 1.f, 128, 128);
    gb.d[1] = mk(Nb, 2048, NbT, 2048, nullptr, N2, N2T, nullptr, 2048, 2048, 2048, 2048, 2048, 1.f, 128, 128);
    gb.d[2] = mk(Mb, 2048, Cb, 2048, nullptr, KP + 512, PT1, nullptr, 2048, 2048, 2048, 512, 2048, 1.f, 128, 128);
    gb.d[3] = mk(NbT, 2048, Rcat, 2048, nullptr, nullptr, Rcat + 512 * 2048, nullptr, 2048, 2048, 2048, 512, 2048, 1.f, 128, 128);
    gemm_bt<128, 128><<<640, 256, 0, stream>>>(gb); }
  // t-vector Horner with M2: td = sum_{k<8} M^k v
  matvec_h<<<512, 256, 0, stream>>>(M2, ta, ta, tb, 2048);
  matvec_h<<<512, 256, 0, stream>>>(M2, tb, ta, tc, 2048);
  matvec_h<<<512, 256, 0, stream>>>(M2, tc, ta, td, 2048);
  // ---- G2: M4 = M2@M2 | [P2|P3] = M2@[Cb;PT1]^T (KP cols 2-3) | [R2;R3] = (N2T@[R0;R1]^T)^T | YH = N2@B_F (Dt) ----
  { GemmBatch gb{}; gb.nd = 4;
    gb.d[0] = mk(M2, 2048, M2T, 2048, nullptr, M4, nullptr, nullptr, 2048, 2048, 2048, 2048, 2048, 1.f, 128, 128);
    gb.d[1] = mk(M2, 2048, Cb, 2048, nullptr, KP + 1024, nullptr, nullptr, 2048, 2048, 2048, 1024, 2048, 1.f, 128, 128);
    gb.d[2] = mk(N2T, 2048, Rcat, 2048, nullptr, nullptr, Rcat + 1024 * 2048, nullptr, 2048, 2048, 2048, 1024, 2048, 1.f, 128, 128);
    gb.d[3] = mk(N2, 2048, BFT, 2048, nullptr, nullptr, YHT, nullptr, 2048, 2048, 2048, 512, 2048, 1.f, 128, 128);
    gemm_bt<128, 128><<<576, 256, 0, stream>>>(gb); }
  // ---- G3: Y = N2@YH (Dt=YT) | Wcat = Rcat@B_F (Dt=WT) ----
  { GemmBatch gb{}; gb.nd = 2;
    gb.d[0] = mk(N2, 2048, YHT, 2048, nullptr, nullptr, YT, nullptr, 2048, 2048, 2048, 512, 2048, 1.f, 128, 64);
    gb.d[1] = mk(Rcat, 2048, BFT, 2048, nullptr, nullptr, WT, nullptr, 2048, 2048, 2048, 512, 2048, 1.f, 128, 64);
    gemm_bt<128, 64><<<256, 256, 0, stream>>>(gb); }
  // ---- G4: W'cat = Rcat@Y (Dt=W2T) | V = KP@Wcat (f32) ----
  { GemmBatch gb{}; gb.nd = 2;
    gb.d[0] = mk(Rcat, 2048, YT, 2048, nullptr, nullptr, W2T, nullptr, 2048, 2048, 2048, 512, 2048, 1.f, 128, 64);
    gb.d[1] = mk(KP, 2048, WT, 2048, nullptr, nullptr, nullptr, Vf, 512, 2048, 2048, 512, 2048, 1.f, 128, 64);
    gemm_bt<128, 64><<<256, 256, 0, stream>>>(gb); }
  // ---- G5: Z = KP@W'cat (Dt=ZT) ----
  { GemmBatch gb{}; gb.nd = 1;
    gb.d[0] = mk(KP, 2048, W2T, 2048, nullptr, nullptr, ZT, nullptr, 2048, 2048, 2048, 512, 2048, 1.f, 64, 64);
    gemm_bt<64, 64><<<256, 256, 0, stream>>>(gb); }
  // ---- G6: B_hat = -(V + M4@Z) -> d_out f32 ----
  { GemmBatch gb{}; gb.nd = 1;
    gb.d[0] = mk(M4, 2048, ZT, 2048, Vf, nullptr, nullptr, out, 512, 2048, 2048, 512, 2048, -1.f, 64, 64);
    gemm_bt<64, 64><<<256, 256, 0, stream>>>(gb); }
  // ---- D_hat ----
  matvec_f32<<<128, 256, 0, stream>>>(Cf, td, uu, 512, 2048);
  dhat_k<<<1024, 256, 0, stream>>>(DFf, uu, out + 2048 * 512);
}